// Round 1
// baseline (720.851 us; speedup 1.0000x reference)
//
#include <hip/hip_runtime.h>
#include <math.h>

// GodContinuousAreaModel: B=32, D_IN=1024, A=4, N_PER=2048, N=8192, OUT=11.
// area_idx = arange(N) (identity permutation) -> all gathers collapse to
// direct indexing. Dominant cost: streaming synapses_w (256 MB f32) once.
// Roofline: ~290 MB / 6.3 TB/s ~= 46 us; f32 VALU FMA floor ~= 31 us.
#define BATCH 32
#define DIN   1024
#define NAREA 4
#define NPER  2048
#define NTOT  8192
#define KC    256          // k-chunk staged in LDS
#define RPB   16           // rows per block (16 | 2048 -> one area per block)
#define SYN_CHUNKS 32      // 8192/256
#define ALL_CHUNKS 36      // + 1024/256 receptor (stim) chunks

typedef __attribute__((address_space(1))) const unsigned int gu32_t;
typedef __attribute__((address_space(3))) unsigned int su32_t;

// async global->LDS, 16B/lane: lane i lands at ldsbase + i*16 (wave-uniform base)
__device__ __forceinline__ void load_lds16(const float* g, float* l) {
  __builtin_amdgcn_global_load_lds((gu32_t*)g, (su32_t*)l, 16, 0, 0);
}

// ---- kernel 1: gsum[a] = sum_{b,n} |Z0[b,a,n]| (gate decided in k_main) ----
__global__ void k_gate(const float* __restrict__ Z0, float* __restrict__ gsum) {
  const int a = blockIdx.x >> 3;       // 4 areas x 8 slices
  const int slice = blockIdx.x & 7;    // 4 batches per slice
  const int tid = threadIdx.x;
  float s = 0.f;
#pragma unroll
  for (int it = 0; it < 8; ++it) {
    const int idx = it * 256 + tid;    // 2048 float4 = 4 b-rows * 512
    const int b = slice * 4 + (idx >> 9);
    const int n4 = idx & 511;
    const float4 z = *(const float4*)(Z0 + (size_t)b * NTOT + a * NPER + n4 * 4);
    s += fabsf(z.x) + fabsf(z.y) + fabsf(z.z) + fabsf(z.w);
  }
#pragma unroll
  for (int off = 32; off > 0; off >>= 1) s += __shfl_down(s, off);
  __shared__ float wsum[4];
  if ((tid & 63) == 0) wsum[tid >> 6] = s;
  __syncthreads();
  if (tid == 0) atomicAdd(&gsum[a], wsum[0] + wsum[1] + wsum[2] + wsum[3]);
}

// ---- kernel 2: fused (scaled-synapse GEMM + stim GEMM + bias + tanh) -------
// Block: 256 thr = 4 waves; block owns 16 rows, all 32 batches.
// Wave w owns rows r0+4w..+3; lanes split k (4 floats each -> coalesced W).
// acc[4][32] per lane holds k-slice partials; epilogue reduces across lanes.
__launch_bounds__(256, 2)
__global__ void k_main(const float* __restrict__ x,  const float* __restrict__ Z0,
                       const float* __restrict__ Rw, const float* __restrict__ rbias,
                       const float* __restrict__ Sw, const float* __restrict__ sbias,
                       const float* __restrict__ gsum, float* __restrict__ Zn) {
  __shared__ __align__(16) float zs[2][BATCH][KC];   // 64 KB double-buffered X chunk
  const int tid = threadIdx.x;
  const int w = tid >> 6, lane = tid & 63;
  const int r0 = blockIdx.x * RPB;
  const int o = r0 / NPER;             // output area of this block
  const int rw0 = r0 + w * 4;

  float gate[NAREA], coeff[NAREA];
#pragma unroll
  for (int a = 0; a < NAREA; ++a) {
    gate[a] = (gsum[a] * (1.f / (BATCH * NPER)) > 0.05f) ? 1.f : 0.f;
    coeff[a] = gate[a] * ((a == o) ? 0.8f : 0.1f);
  }

  float acc[4][BATCH];
#pragma unroll
  for (int i = 0; i < 4; ++i)
#pragma unroll
    for (int b = 0; b < BATCH; ++b) acc[i][b] = 0.f;

  auto stage = [&](int kc, int buf) {
    const float* X; int stride, k0;
    if (kc < SYN_CHUNKS) { X = Z0; stride = NTOT; k0 = kc * KC; }
    else                 { X = x;  stride = DIN;  k0 = (kc - SYN_CHUNKS) * KC; }
    // wave w stages batch rows w*8..w*8+7 (1 KB each, contiguous in LDS)
#pragma unroll
    for (int i = 0; i < 8; ++i) {
      const int b = w * 8 + i;
      load_lds16(X + (size_t)b * stride + k0 + lane * 4, &zs[buf][b][0]);
    }
  };

  stage(0, 0);
  for (int kc = 0; kc < ALL_CHUNKS; ++kc) {
    const int buf = kc & 1;
    __syncthreads();                   // chunk kc staged; buf^1 now free
    if (kc + 1 < ALL_CHUNKS) stage(kc + 1, buf ^ 1);  // async, overlaps compute

    const float* Wm; int strideW, k0; float s;
    if (kc < SYN_CHUNKS) { Wm = Sw; strideW = NTOT; k0 = kc * KC; s = coeff[kc >> 3]; }
    else                 { Wm = Rw; strideW = DIN;  k0 = (kc - SYN_CHUNKS) * KC; s = 1.f; }

    float4 wv[4];
#pragma unroll
    for (int i = 0; i < 4; ++i)
      wv[i] = *(const float4*)(Wm + (size_t)(rw0 + i) * strideW + k0 + lane * 4);
#pragma unroll
    for (int i = 0; i < 4; ++i) { wv[i].x *= s; wv[i].y *= s; wv[i].z *= s; wv[i].w *= s; }

#pragma unroll
    for (int b = 0; b < BATCH; ++b) {
      const float4 z = *(const float4*)&zs[buf][b][lane * 4];
#pragma unroll
      for (int i = 0; i < 4; ++i) {
        acc[i][b] = fmaf(wv[i].x, z.x, acc[i][b]);
        acc[i][b] = fmaf(wv[i].y, z.y, acc[i][b]);
        acc[i][b] = fmaf(wv[i].z, z.z, acc[i][b]);
        acc[i][b] = fmaf(wv[i].w, z.w, acc[i][b]);
      }
    }
  }

  // ---- epilogue: reduce each acc over 64 lanes via LDS transpose + tree ----
  float (*L)[64] = reinterpret_cast<float (*)[64]>(&zs[0][0][0]);  // 256 x 64
  const float gate_o = gate[o];
#pragma unroll 1
  for (int h = 0; h < 2; ++h) {        // batch halves (64 KB LDS per half)
    __syncthreads();
#pragma unroll
    for (int i = 0; i < 4; ++i)
#pragma unroll
      for (int bb = 0; bb < 16; ++bb)
        L[(w * 4 + i) * 16 + bb][lane] = acc[i][h * 16 + bb];  // conflict-free
    __syncthreads();
#pragma unroll
    for (int step = 0; step < 6; ++step) {
      const int off = 32 >> step;
      for (int idx = tid; idx < (off << 8); idx += 256) {
        const int out = idx >> (5 - step);
        const int l = idx & (off - 1);
        L[out][l] += L[out][l + off];
      }
      __syncthreads();
    }
    const int r = r0 + (tid >> 4);
    const int b = h * 16 + (tid & 15);
    const float v = L[tid][0] + rbias[r] + gate_o * sbias[r];
    Zn[(size_t)r * BATCH + b] = tanhf(v);  // Znew stored [r][b]
  }
}

// ---- kernel 3: raw[j,b] partials via atomics (split r 16-way per j) --------
__global__ void k_proj(const float* __restrict__ Zn, const float* __restrict__ olw,
                       float* __restrict__ raw) {
  const int j = blockIdx.x >> 4;       // 0..10
  const int rs = blockIdx.x & 15;      // r-slice of 512
  const int tid = threadIdx.x;
  const int b = tid & 31, stripe = tid >> 5;   // 8 stripes x 64 rows
  const int rbase = rs * 512 + stripe * 64;
  float a = 0.f;
#pragma unroll
  for (int rr = 0; rr < 64; ++rr) {
    const int r = rbase + rr;
    a = fmaf(olw[j * NTOT + r], Zn[(size_t)r * BATCH + b], a);
  }
  __shared__ float red[8][33];
  red[stripe][b] = a;
  __syncthreads();
  if (stripe == 0) {
    float v = 0.f;
#pragma unroll
    for (int s2 = 0; s2 < 8; ++s2) v += red[s2][b];
    atomicAdd(&raw[j * BATCH + b], v);
  }
}

// ---- kernel 4: bias + split logits / sigmoid gate into d_out ---------------
__global__ void k_fin(const float* __restrict__ raw, const float* __restrict__ olb,
                      float* __restrict__ out) {
  const int t = threadIdx.x;
  if (t < 352) {
    const int j = t >> 5, b = t & 31;
    const float v = raw[j * BATCH + b] + olb[j];
    if (j < 10) out[b * 10 + j] = v;            // logits (32,10) row-major
    else        out[320 + b] = 1.f / (1.f + expf(-v));  // out_gate (32,)
  }
}

extern "C" void kernel_launch(void* const* d_in, const int* in_sizes, int n_in,
                              void* d_out, int out_size, void* d_ws, size_t ws_size,
                              hipStream_t stream) {
  const float* x    = (const float*)d_in[0];
  const float* Z0   = (const float*)d_in[1];
  const float* Rw   = (const float*)d_in[2];
  const float* rb_  = (const float*)d_in[3];
  const float* Sw   = (const float*)d_in[4];
  const float* sb_  = (const float*)d_in[5];
  const float* olw  = (const float*)d_in[6];
  const float* olb  = (const float*)d_in[7];
  // d_in[8] (area_idx) is arange(N): identity permutation, not needed.

  float* ws   = (float*)d_ws;
  float* gsum = ws;                 // [4]   gate |Z0| sums
  float* raw  = ws + 8;             // [352] output-lobe accumulators
  float* Zn   = ws + 512;           // [8192*32] Znew, layout [r][b] (1 MB)

  hipMemsetAsync(d_ws, 0, 512 * sizeof(float), stream);  // zero gsum + raw
  k_gate<<<32, 256, 0, stream>>>(Z0, gsum);
  k_main<<<NTOT / RPB, 256, 0, stream>>>(x, Z0, Rw, rb_, Sw, sb_, gsum, Zn);
  k_proj<<<11 * 16, 256, 0, stream>>>(Zn, olw, raw);
  k_fin<<<1, 384, 0, stream>>>(raw, olb, (float*)d_out);
}

// Round 2
// 430.643 us; speedup vs baseline: 1.6739x; 1.6739x over previous
//
#include <hip/hip_runtime.h>
#include <math.h>

// GodContinuousAreaModel: B=32, D_IN=1024, A=4, N_PER=2048, N=8192, OUT=11.
// area_idx = arange(N) (identity permutation) -> all gathers collapse to
// direct indexing. Dominant cost: streaming synapses_w (256 MB f32) once.
// Roofline: ~290 MB / 6.3 TB/s ~= 46 us; f32 VALU FMA floor ~= 31 us.
// R1 lesson: epilogue's dynamically-indexed acc[][h*16+bb] demoted the whole
// accumulator array to scratch (WRITE_SIZE 2.4 GB, VALUBusy 12%). Epilogue is
// now fully unrolled -> all acc indices constant -> acc stays in VGPRs.
#define BATCH 32
#define DIN   1024
#define NAREA 4
#define NPER  2048
#define NTOT  8192
#define KC    256          // k-chunk staged in LDS
#define RPB   16           // rows per block (16 | 2048 -> one area per block)
#define SYN_CHUNKS 32      // 8192/256
#define ALL_CHUNKS 36      // + 1024/256 receptor (stim) chunks

typedef __attribute__((address_space(1))) const unsigned int gu32_t;
typedef __attribute__((address_space(3))) unsigned int su32_t;

// async global->LDS, 16B/lane: lane i lands at ldsbase + i*16 (wave-uniform base)
__device__ __forceinline__ void load_lds16(const float* g, float* l) {
  __builtin_amdgcn_global_load_lds((gu32_t*)g, (su32_t*)l, 16, 0, 0);
}

// ---- kernel 1: gsum[a] = sum_{b,n} |Z0[b,a,n]| (gate decided in k_main) ----
__global__ void k_gate(const float* __restrict__ Z0, float* __restrict__ gsum) {
  const int a = blockIdx.x >> 3;       // 4 areas x 8 slices
  const int slice = blockIdx.x & 7;    // 4 batches per slice
  const int tid = threadIdx.x;
  float s = 0.f;
#pragma unroll
  for (int it = 0; it < 8; ++it) {
    const int idx = it * 256 + tid;    // 2048 float4 = 4 b-rows * 512
    const int b = slice * 4 + (idx >> 9);
    const int n4 = idx & 511;
    const float4 z = *(const float4*)(Z0 + (size_t)b * NTOT + a * NPER + n4 * 4);
    s += fabsf(z.x) + fabsf(z.y) + fabsf(z.z) + fabsf(z.w);
  }
#pragma unroll
  for (int off = 32; off > 0; off >>= 1) s += __shfl_down(s, off);
  __shared__ float wsum[4];
  if ((tid & 63) == 0) wsum[tid >> 6] = s;
  __syncthreads();
  if (tid == 0) atomicAdd(&gsum[a], wsum[0] + wsum[1] + wsum[2] + wsum[3]);
}

// ---- kernel 2: fused (scaled-synapse GEMM + stim GEMM + bias + tanh) -------
// Block: 256 thr = 4 waves; block owns 16 rows, all 32 batches.
// Wave w owns rows r0+4w..+3; lanes split k (4 floats each -> coalesced W).
// acc[4][32] per lane holds k-slice partials; epilogue reduces across lanes.
__launch_bounds__(256, 2)
__global__ void k_main(const float* __restrict__ x,  const float* __restrict__ Z0,
                       const float* __restrict__ Rw, const float* __restrict__ rbias,
                       const float* __restrict__ Sw, const float* __restrict__ sbias,
                       const float* __restrict__ gsum, float* __restrict__ Zn) {
  __shared__ __align__(16) float zs[2][BATCH][KC];   // 64 KB double-buffered X chunk
  const int tid = threadIdx.x;
  const int w = tid >> 6, lane = tid & 63;
  const int r0 = blockIdx.x * RPB;
  const int o = r0 / NPER;             // output area of this block
  const int rw0 = r0 + w * 4;

  float gate[NAREA], coeff[NAREA];
#pragma unroll
  for (int a = 0; a < NAREA; ++a) {
    gate[a] = (gsum[a] * (1.f / (BATCH * NPER)) > 0.05f) ? 1.f : 0.f;
    coeff[a] = gate[a] * ((a == o) ? 0.8f : 0.1f);
  }

  float acc[4][BATCH];
#pragma unroll
  for (int i = 0; i < 4; ++i)
#pragma unroll
    for (int b = 0; b < BATCH; ++b) acc[i][b] = 0.f;

  auto stage = [&](int kc, int buf) {
    const float* X; int stride, k0;
    if (kc < SYN_CHUNKS) { X = Z0; stride = NTOT; k0 = kc * KC; }
    else                 { X = x;  stride = DIN;  k0 = (kc - SYN_CHUNKS) * KC; }
    // wave w stages batch rows w*8..w*8+7 (1 KB each, contiguous in LDS)
#pragma unroll
    for (int i = 0; i < 8; ++i) {
      const int b = w * 8 + i;
      load_lds16(X + (size_t)b * stride + k0 + lane * 4, &zs[buf][b][0]);
    }
  };

  stage(0, 0);
  for (int kc = 0; kc < ALL_CHUNKS; ++kc) {
    const int buf = kc & 1;
    __syncthreads();                   // chunk kc staged; buf^1 now free
    if (kc + 1 < ALL_CHUNKS) stage(kc + 1, buf ^ 1);  // async, overlaps compute

    const float* Wm; int strideW, k0; float s;
    if (kc < SYN_CHUNKS) { Wm = Sw; strideW = NTOT; k0 = kc * KC; s = coeff[kc >> 3]; }
    else                 { Wm = Rw; strideW = DIN;  k0 = (kc - SYN_CHUNKS) * KC; s = 1.f; }

    float4 wv[4];
#pragma unroll
    for (int i = 0; i < 4; ++i)
      wv[i] = *(const float4*)(Wm + (size_t)(rw0 + i) * strideW + k0 + lane * 4);
#pragma unroll
    for (int i = 0; i < 4; ++i) { wv[i].x *= s; wv[i].y *= s; wv[i].z *= s; wv[i].w *= s; }

#pragma unroll
    for (int b = 0; b < BATCH; ++b) {
      const float4 z = *(const float4*)&zs[buf][b][lane * 4];
#pragma unroll
      for (int i = 0; i < 4; ++i) {
        acc[i][b] = fmaf(wv[i].x, z.x, acc[i][b]);
        acc[i][b] = fmaf(wv[i].y, z.y, acc[i][b]);
        acc[i][b] = fmaf(wv[i].z, z.z, acc[i][b]);
        acc[i][b] = fmaf(wv[i].w, z.w, acc[i][b]);
      }
    }
  }

  // ---- epilogue: reduce each acc over 64 lanes via LDS transpose + tree ----
  // FULLY UNROLLED over h (R1: runtime h forced acc into scratch memory).
  float (*L)[64] = reinterpret_cast<float (*)[64]>(&zs[0][0][0]);  // 256 x 64
  const float gate_o = gate[o];
#pragma unroll
  for (int h = 0; h < 2; ++h) {        // batch halves (64 KB LDS per half)
    __syncthreads();
#pragma unroll
    for (int i = 0; i < 4; ++i)
#pragma unroll
      for (int bb = 0; bb < 16; ++bb)
        L[(w * 4 + i) * 16 + bb][lane] = acc[i][h * 16 + bb];  // conflict-free
    __syncthreads();
#pragma unroll
    for (int step = 0; step < 6; ++step) {
      const int off = 32 >> step;
      for (int idx = tid; idx < (off << 8); idx += 256) {
        const int out = idx >> (5 - step);
        const int l = idx & (off - 1);
        L[out][l] += L[out][l + off];
      }
      __syncthreads();
    }
    const int r = r0 + (tid >> 4);
    const int b = h * 16 + (tid & 15);
    const float v = L[tid][0] + rbias[r] + gate_o * sbias[r];
    Zn[(size_t)r * BATCH + b] = tanhf(v);  // Znew stored [r][b]
  }
}

// ---- kernel 3: raw[j,b] partials via atomics (split r 16-way per j) --------
__global__ void k_proj(const float* __restrict__ Zn, const float* __restrict__ olw,
                       float* __restrict__ raw) {
  const int j = blockIdx.x >> 4;       // 0..10
  const int rs = blockIdx.x & 15;      // r-slice of 512
  const int tid = threadIdx.x;
  const int b = tid & 31, stripe = tid >> 5;   // 8 stripes x 64 rows
  const int rbase = rs * 512 + stripe * 64;
  float a = 0.f;
#pragma unroll
  for (int rr = 0; rr < 64; ++rr) {
    const int r = rbase + rr;
    a = fmaf(olw[j * NTOT + r], Zn[(size_t)r * BATCH + b], a);
  }
  __shared__ float red[8][33];
  red[stripe][b] = a;
  __syncthreads();
  if (stripe == 0) {
    float v = 0.f;
#pragma unroll
    for (int s2 = 0; s2 < 8; ++s2) v += red[s2][b];
    atomicAdd(&raw[j * BATCH + b], v);
  }
}

// ---- kernel 4: bias + split logits / sigmoid gate into d_out ---------------
__global__ void k_fin(const float* __restrict__ raw, const float* __restrict__ olb,
                      float* __restrict__ out) {
  const int t = threadIdx.x;
  if (t < 352) {
    const int j = t >> 5, b = t & 31;
    const float v = raw[j * BATCH + b] + olb[j];
    if (j < 10) out[b * 10 + j] = v;            // logits (32,10) row-major
    else        out[320 + b] = 1.f / (1.f + expf(-v));  // out_gate (32,)
  }
}

extern "C" void kernel_launch(void* const* d_in, const int* in_sizes, int n_in,
                              void* d_out, int out_size, void* d_ws, size_t ws_size,
                              hipStream_t stream) {
  const float* x    = (const float*)d_in[0];
  const float* Z0   = (const float*)d_in[1];
  const float* Rw   = (const float*)d_in[2];
  const float* rb_  = (const float*)d_in[3];
  const float* Sw   = (const float*)d_in[4];
  const float* sb_  = (const float*)d_in[5];
  const float* olw  = (const float*)d_in[6];
  const float* olb  = (const float*)d_in[7];
  // d_in[8] (area_idx) is arange(N): identity permutation, not needed.

  float* ws   = (float*)d_ws;
  float* gsum = ws;                 // [4]   gate |Z0| sums
  float* raw  = ws + 8;             // [352] output-lobe accumulators
  float* Zn   = ws + 512;           // [8192*32] Znew, layout [r][b] (1 MB)

  hipMemsetAsync(d_ws, 0, 512 * sizeof(float), stream);  // zero gsum + raw
  k_gate<<<32, 256, 0, stream>>>(Z0, gsum);
  k_main<<<NTOT / RPB, 256, 0, stream>>>(x, Z0, Rw, rb_, Sw, sb_, gsum, Zn);
  k_proj<<<11 * 16, 256, 0, stream>>>(Zn, olw, raw);
  k_fin<<<1, 384, 0, stream>>>(raw, olb, (float*)d_out);
}

// Round 3
// 421.213 us; speedup vs baseline: 1.7114x; 1.0224x over previous
//
#include <hip/hip_runtime.h>
#include <math.h>

// GodContinuousAreaModel: B=32, D_IN=1024, A=4, N_PER=2048, N=8192, OUT=11.
// area_idx = arange(N) (identity) -> direct indexing. Dominant cost: stream
// synapses_w (256 MB f32) once. Roofline ~290 MB / 6.3 TB/s ~= 46 us.
// R1: dynamic acc index -> scratch spill (WRITE 2.4 GB). Fixed R2.
// R2: VALU-FMA design collides with LDS ceiling (256 KB/CU/chunk re-read),
//     f32-FMA VALU floor (31 us) and per-chunk barrier drain -> ~150 us.
// R3: bf16 MFMA, barrier-free K-loop. A-frags straight from the HBM W-stream
//     (converted f32->bf16 in-register), B-frags from a precomputed bf16 Zg
//     buffer (576 KB, L2-resident). No __syncthreads in the K-loop; one
//     epilogue barrier. Matrix pipe does the math; HBM is the only ceiling.
#define BATCH 32
#define DIN   1024
#define NPER  2048
#define NTOT  8192
#define KTOT  9216          // 8192 synapse + 1024 receptor columns
#define NCHUNK 288          // KTOT / 32

typedef __attribute__((ext_vector_type(8))) short short8;   // 8 bf16 = 4 VGPRs
typedef __attribute__((ext_vector_type(4))) float f32x4;

__device__ __forceinline__ unsigned short f2bf(float f) {   // RNE f32->bf16
  unsigned u = __float_as_uint(f);
  u += 0x7FFF + ((u >> 16) & 1);
  return (unsigned short)(u >> 16);
}

// ---- kernel 1: gsum[a] = sum_{b,n} |Z0[b,a,n]| ----------------------------
__global__ void k_gate(const float* __restrict__ Z0, float* __restrict__ gsum) {
  const int a = blockIdx.x >> 3;       // 4 areas x 8 slices
  const int slice = blockIdx.x & 7;    // 4 batches per slice
  const int tid = threadIdx.x;
  float s = 0.f;
#pragma unroll
  for (int it = 0; it < 8; ++it) {
    const int idx = it * 256 + tid;
    const int b = slice * 4 + (idx >> 9);
    const int n4 = idx & 511;
    const float4 z = *(const float4*)(Z0 + (size_t)b * NTOT + a * NPER + n4 * 4);
    s += fabsf(z.x) + fabsf(z.y) + fabsf(z.z) + fabsf(z.w);
  }
#pragma unroll
  for (int off = 32; off > 0; off >>= 1) s += __shfl_down(s, off);
  __shared__ float wsum[4];
  if ((tid & 63) == 0) wsum[tid >> 6] = s;
  __syncthreads();
  if (tid == 0) atomicAdd(&gsum[a], wsum[0] + wsum[1] + wsum[2] + wsum[3]);
}

// ---- kernel 2: Zg[b][k] = bf16( gate-scaled Z0 | x ), k-major, K=9216 ------
__global__ void k_prep(const float* __restrict__ Z0, const float* __restrict__ x,
                       const float* __restrict__ gsum, unsigned short* __restrict__ zg) {
  const int idx = blockIdx.x * 256 + threadIdx.x;   // 73728 threads, 4 elems each
  const int b = idx / (KTOT / 4);
  const int k = (idx % (KTOT / 4)) * 4;
  float4 v; float g;
  if (k < NTOT) {
    v = *(const float4*)(Z0 + (size_t)b * NTOT + k);
    g = (gsum[k >> 11] * (1.f / (BATCH * NPER)) > 0.05f) ? 1.f : 0.f;
  } else {
    v = *(const float4*)(x + (size_t)b * DIN + (k - NTOT));
    g = 1.f;
  }
  ushort4 o;
  o.x = f2bf(v.x * g); o.y = f2bf(v.y * g);
  o.z = f2bf(v.z * g); o.w = f2bf(v.w * g);
  *(ushort4*)(zg + (size_t)b * KTOT + k) = o;
}

// ---- kernel 3: MFMA GEMM  Znext[r][b] = sum_k coeff*W[r,k]*Zg[b,k] ---------
// 512 blocks x 512 thr (8 waves). Block owns 16 rows; wave w owns k-chunks
// c = w, w+8, ... (36 chunks of 32). No barrier in the K-loop. Fragment maps
// (learn_hip-verified): A[m=lane&15][k=quad*8+j], B[n=lane&15][k=quad*8+j],
// D[row=quad*4+reg][col=lane&15].
__launch_bounds__(512, 4)
__global__ void k_main(const float* __restrict__ Rw, const float* __restrict__ rbias,
                       const float* __restrict__ Sw, const float* __restrict__ sbias,
                       const float* __restrict__ gsum, const unsigned short* __restrict__ zg,
                       float* __restrict__ Zn) {
  const int tid = threadIdx.x;
  const int w = tid >> 6, lane = tid & 63;
  const int m = lane & 15, quad = lane >> 4;
  const int r0 = blockIdx.x * 16;
  const int o = r0 >> 11;              // output area of this block

  float g[4];
#pragma unroll
  for (int a = 0; a < 4; ++a)
    g[a] = (gsum[a] * (1.f / (BATCH * NPER)) > 0.05f) ? 1.f : 0.f;
  const float c0 = g[0] * ((o == 0) ? 0.8f : 0.1f);
  const float c1 = g[1] * ((o == 1) ? 0.8f : 0.1f);
  const float c2 = g[2] * ((o == 2) ? 0.8f : 0.1f);
  const float c3 = g[3] * ((o == 3) ? 0.8f : 0.1f);

  const float* swrow = Sw + (size_t)(r0 + m) * NTOT;   // A row for this lane
  const float* rwrow = Rw + (size_t)(r0 + m) * DIN;
  const unsigned short* zg0 = zg + (size_t)m * KTOT;          // B rows (batch m, m+16)
  const unsigned short* zg1 = zg + (size_t)(m + 16) * KTOT;

  f32x4 acc0 = {0.f, 0.f, 0.f, 0.f};   // n = 0..15
  f32x4 acc1 = {0.f, 0.f, 0.f, 0.f};   // n = 16..31

  for (int c = w; c < NCHUNK; c += 8) {
    const int k0 = c * 32;
    const float* ap; float s;
    if (k0 < NTOT) {                    // wave-uniform branch
      ap = swrow + k0;
      const int a = k0 >> 11;
      s = (a == 0) ? c0 : (a == 1) ? c1 : (a == 2) ? c2 : c3;
    } else {
      ap = rwrow + (k0 - NTOT);
      s = 1.f;
    }
    const float4 wv0 = *(const float4*)(ap + quad * 8);
    const float4 wv1 = *(const float4*)(ap + quad * 8 + 4);
    short8 af;
    af[0] = (short)f2bf(wv0.x * s); af[1] = (short)f2bf(wv0.y * s);
    af[2] = (short)f2bf(wv0.z * s); af[3] = (short)f2bf(wv0.w * s);
    af[4] = (short)f2bf(wv1.x * s); af[5] = (short)f2bf(wv1.y * s);
    af[6] = (short)f2bf(wv1.z * s); af[7] = (short)f2bf(wv1.w * s);
    const short8 bf0 = *(const short8*)(zg0 + k0 + quad * 8);  // L2-hot
    const short8 bf1 = *(const short8*)(zg1 + k0 + quad * 8);
    acc0 = __builtin_amdgcn_mfma_f32_16x16x32_bf16(af, bf0, acc0, 0, 0, 0);
    acc1 = __builtin_amdgcn_mfma_f32_16x16x32_bf16(af, bf1, acc1, 0, 0, 0);
  }

  // ---- epilogue: sum the 8 waves' K-partials, bias + tanh + store ----------
  __shared__ float red[8][2][16][16];   // 16 KB
#pragma unroll
  for (int r = 0; r < 4; ++r) {
    red[w][0][quad * 4 + r][m] = acc0[r];
    red[w][1][quad * 4 + r][m] = acc1[r];
  }
  __syncthreads();
  const int mrow = tid >> 5, n = tid & 31;         // 512 outputs, 512 threads
  const int f = n >> 4, nn = n & 15;
  float v = 0.f;
#pragma unroll
  for (int ww = 0; ww < 8; ++ww) v += red[ww][f][mrow][nn];
  const int r = r0 + mrow;
  const float gate_o = (o == 0) ? g[0] : (o == 1) ? g[1] : (o == 2) ? g[2] : g[3];
  v += rbias[r] + gate_o * sbias[r];
  Zn[(size_t)r * BATCH + n] = tanhf(v);            // Znew stored [r][b]
}

// ---- kernel 4: raw[j,b] partials via atomics (split r 16-way per j) --------
__global__ void k_proj(const float* __restrict__ Zn, const float* __restrict__ olw,
                       float* __restrict__ raw) {
  const int j = blockIdx.x >> 4;       // 0..10
  const int rs = blockIdx.x & 15;      // r-slice of 512
  const int tid = threadIdx.x;
  const int b = tid & 31, stripe = tid >> 5;   // 8 stripes x 64 rows
  const int rbase = rs * 512 + stripe * 64;
  float a = 0.f;
#pragma unroll
  for (int rr = 0; rr < 64; ++rr) {
    const int r = rbase + rr;
    a = fmaf(olw[j * NTOT + r], Zn[(size_t)r * BATCH + b], a);
  }
  __shared__ float red[8][33];
  red[stripe][b] = a;
  __syncthreads();
  if (stripe == 0) {
    float v = 0.f;
#pragma unroll
    for (int s2 = 0; s2 < 8; ++s2) v += red[s2][b];
    atomicAdd(&raw[j * BATCH + b], v);
  }
}

// ---- kernel 5: bias + split logits / sigmoid gate into d_out ---------------
__global__ void k_fin(const float* __restrict__ raw, const float* __restrict__ olb,
                      float* __restrict__ out) {
  const int t = threadIdx.x;
  if (t < 352) {
    const int j = t >> 5, b = t & 31;
    const float v = raw[j * BATCH + b] + olb[j];
    if (j < 10) out[b * 10 + j] = v;            // logits (32,10) row-major
    else        out[320 + b] = 1.f / (1.f + expf(-v));  // out_gate (32,)
  }
}

extern "C" void kernel_launch(void* const* d_in, const int* in_sizes, int n_in,
                              void* d_out, int out_size, void* d_ws, size_t ws_size,
                              hipStream_t stream) {
  const float* x    = (const float*)d_in[0];
  const float* Z0   = (const float*)d_in[1];
  const float* Rw   = (const float*)d_in[2];
  const float* rb_  = (const float*)d_in[3];
  const float* Sw   = (const float*)d_in[4];
  const float* sb_  = (const float*)d_in[5];
  const float* olw  = (const float*)d_in[6];
  const float* olb  = (const float*)d_in[7];
  // d_in[8] (area_idx) is arange(N): identity permutation, not needed.

  float* ws   = (float*)d_ws;
  float* gsum = ws;                 // [4]    gate |Z0| sums
  float* raw  = ws + 8;             // [352]  output-lobe accumulators
  float* Zn   = ws + 512;           // [8192*32] Znew, [r][b] (1 MB)
  unsigned short* zg = (unsigned short*)(ws + 512 + NTOT * BATCH);  // [32][9216] bf16

  hipMemsetAsync(d_ws, 0, 512 * sizeof(float), stream);  // zero gsum + raw
  k_gate<<<32, 256, 0, stream>>>(Z0, gsum);
  k_prep<<<BATCH * KTOT / 1024, 256, 0, stream>>>(Z0, x, gsum, zg);
  k_main<<<NTOT / 16, 512, 0, stream>>>(Rw, rb_, Sw, sb_, gsum, zg, Zn);
  k_proj<<<11 * 16, 256, 0, stream>>>(Zn, olw, raw);
  k_fin<<<1, 384, 0, stream>>>(raw, olb, (float*)d_out);
}

// Round 4
// 410.644 us; speedup vs baseline: 1.7554x; 1.0257x over previous
//
#include <hip/hip_runtime.h>
#include <math.h>

// GodContinuousAreaModel: B=32, D_IN=1024, A=4, N_PER=2048, N=8192, OUT=11.
// area_idx = arange(N) (identity) -> direct indexing. Dominant cost: stream
// synapses_w (256 MB f32) once. Roofline ~290 MB / 6.3 TB/s ~= 46 us.
// R1: dynamic acc index -> scratch spill (WRITE 2.4 GB). Fixed R2.
// R2: VALU-FMA design: ~167 us (VALU floor + LDS re-read + barrier drain).
// R3: MFMA with direct-to-reg A-frags: ~154 us. 16-segment scattered loads
//     (16 rows x 64 B per instr) ran the HBM stream at only 1.9 TB/s --
//     per-tag bytes too low, outstanding-miss tags exhausted (vs m97's
//     proven contiguous global_load_lds stream).
// R4: m97-style: W staged to LDS via global_load_lds (1 KB contiguous per
//     instr, dbuf, pad-to-260 rows = conflict-free b128 reads), A-frags from
//     LDS (f32->bf16 in-reg, coeff folded), B-frags direct from L2-hot zg.
#define BATCH 32
#define DIN   1024
#define NPER  2048
#define NTOT  8192
#define KTOT  9216          // 8192 synapse + 1024 receptor columns
#define KC    256           // k-chunk
#define NCH   36            // KTOT / KC  (32 synapse + 4 receptor chunks)
#define AROW  260           // padded LDS row: m*260%32 = 4m -> uniform banks

typedef __attribute__((ext_vector_type(8))) short short8;   // 8 bf16
typedef __attribute__((ext_vector_type(4))) float f32x4;

typedef __attribute__((address_space(1))) const unsigned int gu32_t;
typedef __attribute__((address_space(3))) unsigned int su32_t;

__device__ __forceinline__ void load_lds16(const float* g, float* l) {
  __builtin_amdgcn_global_load_lds((gu32_t*)g, (su32_t*)l, 16, 0, 0);
}

__device__ __forceinline__ unsigned short f2bf(float f) {   // RNE f32->bf16
  unsigned u = __float_as_uint(f);
  u += 0x7FFF + ((u >> 16) & 1);
  return (unsigned short)(u >> 16);
}

// ---- kernel 1: gsum[a] = sum_{b,n} |Z0[b,a,n]| ----------------------------
__global__ void k_gate(const float* __restrict__ Z0, float* __restrict__ gsum) {
  const int a = blockIdx.x >> 3;
  const int slice = blockIdx.x & 7;
  const int tid = threadIdx.x;
  float s = 0.f;
#pragma unroll
  for (int it = 0; it < 8; ++it) {
    const int idx = it * 256 + tid;
    const int b = slice * 4 + (idx >> 9);
    const int n4 = idx & 511;
    const float4 z = *(const float4*)(Z0 + (size_t)b * NTOT + a * NPER + n4 * 4);
    s += fabsf(z.x) + fabsf(z.y) + fabsf(z.z) + fabsf(z.w);
  }
#pragma unroll
  for (int off = 32; off > 0; off >>= 1) s += __shfl_down(s, off);
  __shared__ float wsum[4];
  if ((tid & 63) == 0) wsum[tid >> 6] = s;
  __syncthreads();
  if (tid == 0) atomicAdd(&gsum[a], wsum[0] + wsum[1] + wsum[2] + wsum[3]);
}

// ---- kernel 2: Zg[b][k] = bf16( gate-scaled Z0 | x ), K=9216 --------------
__global__ void k_prep(const float* __restrict__ Z0, const float* __restrict__ x,
                       const float* __restrict__ gsum, unsigned short* __restrict__ zg) {
  const int idx = blockIdx.x * 256 + threadIdx.x;
  const int b = idx / (KTOT / 4);
  const int k = (idx % (KTOT / 4)) * 4;
  float4 v; float g;
  if (k < NTOT) {
    v = *(const float4*)(Z0 + (size_t)b * NTOT + k);
    g = (gsum[k >> 11] * (1.f / (BATCH * NPER)) > 0.05f) ? 1.f : 0.f;
  } else {
    v = *(const float4*)(x + (size_t)b * DIN + (k - NTOT));
    g = 1.f;
  }
  ushort4 o;
  o.x = f2bf(v.x * g); o.y = f2bf(v.y * g);
  o.z = f2bf(v.z * g); o.w = f2bf(v.w * g);
  *(ushort4*)(zg + (size_t)b * KTOT + k) = o;
}

// ---- kernel 3: MFMA GEMM, m97-style staged A-stream ------------------------
// 512 blocks x 256 thr (4 waves). Block owns 16 rows, all 32 batches, full K.
// Per 256-k chunk: 16 global_load_lds (1 KB contiguous each, one per row,
// dbuf) stage W f32 -> LDS; wave w computes k-subchunks 2w, 2w+1 (A-frags
// via ds_read_b128 from padded LDS rows, f32->bf16 with coeff folded);
// B-frags (bf16) direct from zg (L2-resident, 576 KB). Epilogue reduces the
// 4 waves' K-partials. MFMA maps (learn_hip-verified): A[m=lane&15][k=q*8+j],
// B[n=lane&15][k=q*8+j], D[row=q*4+reg][col=lane&15].
__launch_bounds__(256, 4)
__global__ void k_main(const float* __restrict__ Rw, const float* __restrict__ rbias,
                       const float* __restrict__ Sw, const float* __restrict__ sbias,
                       const float* __restrict__ gsum, const unsigned short* __restrict__ zg,
                       float* __restrict__ Zn) {
  __shared__ __align__(16) float As[2][16][AROW];   // 33.3 KB dbuf W tile
  __shared__ float red[8][16][17];                  // 8.7 KB epilogue
  const int tid = threadIdx.x;
  const int w = tid >> 6, lane = tid & 63;
  const int m = lane & 15, quad = lane >> 4;
  const int r0 = blockIdx.x * 16;
  const int o = r0 >> 11;              // output area of this block

  float g[4], coeff[4];
#pragma unroll
  for (int a = 0; a < 4; ++a) {
    g[a] = (gsum[a] * (1.f / (BATCH * NPER)) > 0.05f) ? 1.f : 0.f;
    coeff[a] = g[a] * ((a == o) ? 0.8f : 0.1f);
  }

  // wave w stages rows 4w..4w+3 of the next chunk (1 KB contiguous each)
  auto stage = [&](int c, int buf) {
    const int k0 = c * KC;
    const float* base; int rs;
    if (k0 < NTOT) { base = Sw + (size_t)r0 * NTOT + k0;          rs = NTOT; }
    else           { base = Rw + (size_t)r0 * DIN + (k0 - NTOT);  rs = DIN;  }
#pragma unroll
    for (int i = 0; i < 4; ++i) {
      const int r = w * 4 + i;
      load_lds16(base + (size_t)r * rs + lane * 4, &As[buf][r][0]);
    }
  };

  f32x4 acc0 = {0.f, 0.f, 0.f, 0.f};   // n = 0..15
  f32x4 acc1 = {0.f, 0.f, 0.f, 0.f};   // n = 16..31

  const unsigned short* zg0 = zg + (size_t)m * KTOT;
  const unsigned short* zg1 = zg + (size_t)(m + 16) * KTOT;

  stage(0, 0);
  for (int c = 0; c < NCH; ++c) {
    const int buf = c & 1;
    __syncthreads();                   // chunk c staged; other buf free
    if (c + 1 < NCH) stage(c + 1, buf ^ 1);   // async, overlaps compute
    const float s = (c < 32) ? coeff[c >> 3] : 1.f;
#pragma unroll
    for (int u = 0; u < 2; ++u) {
      const int ks = (w * 2 + u) * 32;            // k-offset within chunk
      const float* ap = &As[buf][m][ks + quad * 8];
      const float4 a0 = *(const float4*)ap;       // ds_read_b128, uniform banks
      const float4 a1 = *(const float4*)(ap + 4);
      short8 af;
      af[0] = (short)f2bf(a0.x * s); af[1] = (short)f2bf(a0.y * s);
      af[2] = (short)f2bf(a0.z * s); af[3] = (short)f2bf(a0.w * s);
      af[4] = (short)f2bf(a1.x * s); af[5] = (short)f2bf(a1.y * s);
      af[6] = (short)f2bf(a1.z * s); af[7] = (short)f2bf(a1.w * s);
      const int kg = c * KC + ks + quad * 8;      // global k for B
      const short8 b0 = *(const short8*)(zg0 + kg);   // L2-hot
      const short8 b1 = *(const short8*)(zg1 + kg);
      acc0 = __builtin_amdgcn_mfma_f32_16x16x32_bf16(af, b0, acc0, 0, 0, 0);
      acc1 = __builtin_amdgcn_mfma_f32_16x16x32_bf16(af, b1, acc1, 0, 0, 0);
    }
  }

  // ---- epilogue: sum 4 waves' K-partials, bias + tanh + store --------------
#pragma unroll
  for (int r = 0; r < 4; ++r) {
    red[w * 2 + 0][quad * 4 + r][m] = acc0[r];
    red[w * 2 + 1][quad * 4 + r][m] = acc1[r];
  }
  __syncthreads();
  const float gate_o = g[o];
#pragma unroll
  for (int t = tid; t < 512; t += 256) {
    const int row = t >> 5, n = t & 31;
    const int h = n >> 4, nn = n & 15;
    float v = red[0 + h][row][nn] + red[2 + h][row][nn] +
              red[4 + h][row][nn] + red[6 + h][row][nn];
    const int r = r0 + row;
    v += rbias[r] + gate_o * sbias[r];
    Zn[(size_t)r * BATCH + n] = tanhf(v);         // Znew stored [r][b]
  }
}

// ---- kernel 4: raw[j,b] partials via atomics (split r 16-way per j) --------
__global__ void k_proj(const float* __restrict__ Zn, const float* __restrict__ olw,
                       float* __restrict__ raw) {
  const int j = blockIdx.x >> 4;
  const int rs = blockIdx.x & 15;
  const int tid = threadIdx.x;
  const int b = tid & 31, stripe = tid >> 5;
  const int rbase = rs * 512 + stripe * 64;
  float a = 0.f;
#pragma unroll
  for (int rr = 0; rr < 64; ++rr) {
    const int r = rbase + rr;
    a = fmaf(olw[j * NTOT + r], Zn[(size_t)r * BATCH + b], a);
  }
  __shared__ float red[8][33];
  red[stripe][b] = a;
  __syncthreads();
  if (stripe == 0) {
    float v = 0.f;
#pragma unroll
    for (int s2 = 0; s2 < 8; ++s2) v += red[s2][b];
    atomicAdd(&raw[j * BATCH + b], v);
  }
}

// ---- kernel 5: bias + split logits / sigmoid gate into d_out ---------------
__global__ void k_fin(const float* __restrict__ raw, const float* __restrict__ olb,
                      float* __restrict__ out) {
  const int t = threadIdx.x;
  if (t < 352) {
    const int j = t >> 5, b = t & 31;
    const float v = raw[j * BATCH + b] + olb[j];
    if (j < 10) out[b * 10 + j] = v;
    else        out[320 + b] = 1.f / (1.f + expf(-v));
  }
}

extern "C" void kernel_launch(void* const* d_in, const int* in_sizes, int n_in,
                              void* d_out, int out_size, void* d_ws, size_t ws_size,
                              hipStream_t stream) {
  const float* x    = (const float*)d_in[0];
  const float* Z0   = (const float*)d_in[1];
  const float* Rw   = (const float*)d_in[2];
  const float* rb_  = (const float*)d_in[3];
  const float* Sw   = (const float*)d_in[4];
  const float* sb_  = (const float*)d_in[5];
  const float* olw  = (const float*)d_in[6];
  const float* olb  = (const float*)d_in[7];
  // d_in[8] (area_idx) is arange(N): identity permutation, not needed.

  float* ws   = (float*)d_ws;
  float* gsum = ws;                 // [4]    gate |Z0| sums
  float* raw  = ws + 8;             // [352]  output-lobe accumulators
  float* Zn   = ws + 512;           // [8192*32] Znew, [r][b] (1 MB)
  unsigned short* zg = (unsigned short*)(ws + 512 + NTOT * BATCH);  // [32][9216] bf16

  hipMemsetAsync(d_ws, 0, 512 * sizeof(float), stream);  // zero gsum + raw
  k_gate<<<32, 256, 0, stream>>>(Z0, gsum);
  k_prep<<<BATCH * KTOT / 1024, 256, 0, stream>>>(Z0, x, gsum, zg);
  k_main<<<NTOT / 16, 256, 0, stream>>>(Rw, rb_, Sw, sb_, gsum, zg, Zn);
  k_proj<<<11 * 16, 256, 0, stream>>>(Zn, olw, raw);
  k_fin<<<1, 384, 0, stream>>>(raw, olb, (float*)d_out);
}